// Round 3
// baseline (4289.397 us; speedup 1.0000x reference)
//
#include <hip/hip_runtime.h>
#include <stdint.h>

// ---------------------------------------------------------------------------
// StageNet forward on MI355X — ROUND 14.
// R13: 3490us. k_scan 2729us: MSHR/latency wall — each of 16 blocks re-streams
// the full 1.25MB Wr slab per step = 20K L2 lines/CU/step at ~300cy latency,
// ~64 in flight -> ~94K cyc/step. B-split can't fix (per-CU lines invariant).
// This round: g-split so Wr is LDS-RESIDENT (loaded once):
//  * permuted g-space: g' = 16+4h+q groups the 4 gate banks of each h.
//  * k_scan2: 192 blocks = 16 b-groups x 12 g-slices; 113KB Wr slab in LDS;
//    A=Wr,B=h MFMA -> each lane holds the 4 gate pre-acts of one (h,b) in
//    regs; gates in-register (1 c-cell/lane); fm/im computed redundantly.
//    Per step: stage 12.3KB h (double-buffered global) + 8B XK/lane (reg
//    prefetch) + 12 MFMA + gates + per-group 12-block atomic barrier
//    (monotonic counter, agent-scope, XCD-aligned swizzle).
//  * XKb layout now [t][b][g'] (k_gemm_xk epilogue permutes).
//  * k_gemm_xk grid swapped (m fast, g slow): Wk panel stays L2/LLC-hot
//    (FETCH was 927MB ~ 34x Wk re-fetch).
// Predicted: k_scan2 120-300us, gemm ~500us, total ~0.9-1.0ms.
// ---------------------------------------------------------------------------

typedef unsigned short u16;
typedef short bf16x8 __attribute__((ext_vector_type(8)));
typedef float f32x4 __attribute__((ext_vector_type(4)));

#define GLL(gp, lp)                                                            \
  __builtin_amdgcn_global_load_lds(                                            \
      (const __attribute__((address_space(1))) unsigned int*)(gp),             \
      (__attribute__((address_space(3))) unsigned int*)(lp), 16, 0, 0)

__device__ __forceinline__ float bf2f(u16 u) {
  union { unsigned int i; float f; } v;
  v.i = ((unsigned int)u) << 16;
  return v.f;
}
__device__ __forceinline__ u16 f2bf(float f) {
  union { float f; unsigned int i; } v;
  v.f = f;
  unsigned int r = (v.i + 0x7fffu + ((v.i >> 16) & 1u)) >> 16;
  return (u16)r;
}
__device__ __forceinline__ float ldf(const void* p, size_t i, int isbf) {
  return isbf ? bf2f(((const u16*)p)[i]) : ((const float*)p)[i];
}
__device__ __forceinline__ float sigf(float x) { return 1.f / (1.f + __expf(-x)); }
__device__ __forceinline__ float tanhf_(float x) {
  float cx = fminf(fmaxf(x, -15.f), 15.f);
  float e = __expf(2.f * cx);
  return (e - 1.f) / (e + 1.f);
}
__device__ __forceinline__ float dot8_bf(const u16* w, const float* lp) {
  uint4 wv = *(const uint4*)w;
  union { unsigned int u; float f; } a0, a1;
  float s;
  a0.u = wv.x << 16; a1.u = wv.x & 0xffff0000u;
  s = lp[0] * a0.f + lp[1] * a1.f;
  a0.u = wv.y << 16; a1.u = wv.y & 0xffff0000u;
  s += lp[2] * a0.f + lp[3] * a1.f;
  a0.u = wv.z << 16; a1.u = wv.z & 0xffff0000u;
  s += lp[4] * a0.f + lp[5] * a1.f;
  a0.u = wv.w << 16; a1.u = wv.w & 0xffff0000u;
  s += lp[6] * a0.f + lp[7] * a1.f;
  return s;
}

// ------------------------- dtype detection (safety) ------------------------
__global__ void k_detect(const unsigned int* __restrict__ emb_raw,
                         int* __restrict__ flag) {
  if (blockIdx.x == 0 && threadIdx.x == 0) {
    int cnt = 0;
    for (int i = 64; i < 128; ++i) {
      unsigned int u = emb_raw[i];
      unsigned int lo = u & 0xffffu;
      unsigned int ex = (lo >> 7) & 0xffu;
      if (lo != 0 && ex >= 100 && ex <= 126) ++cnt;
    }
    *flag = (cnt >= 32) ? 1 : 0;
  }
}

// ------------------------- canonicalization --------------------------------
__global__ void k_cvt_emb(const void* __restrict__ src, u16* __restrict__ dst,
                          const int* __restrict__ flagp) {
  int isbf = *flagp;
  int n = 10001 * 128;
  int i = blockIdx.x * blockDim.x + threadIdx.x;
  int stride = gridDim.x * blockDim.x;
  for (; i < n; i += stride)
    dst[i] = isbf ? ((const u16*)src)[i] : f2bf(((const float*)src)[i]);
}

__global__ void k_repack_wk(const void* __restrict__ wk, u16* __restrict__ wkp,
                            const int* __restrict__ flagp) {
  int isbf = *flagp;
  size_t i = (size_t)blockIdx.x * blockDim.x + threadIdx.x;
  size_t total = (size_t)1664 * 8192;
  size_t stride = (size_t)gridDim.x * blockDim.x;
  for (; i < total; i += stride) {
    size_t g = i >> 13, k = i & 8191;
    wkp[i] = (g < 1552) ? f2bf(ldf(wk, g * 8193 + k, isbf)) : (u16)0;
  }
}

// wrP2[g'][k] bf16 (permuted g'): g'<16 -> g'=g ; else g'=16+4h+q <-> g=16+q*384+h
__global__ void k_prep_wr2(const void* __restrict__ wr, const void* __restrict__ wk,
                           const void* __restrict__ bk, const void* __restrict__ br,
                           u16* __restrict__ wrP2, float* __restrict__ biasC,
                           float* __restrict__ wlC, const int* __restrict__ flagp) {
  int isbf = *flagp;
  int i0 = blockIdx.x * blockDim.x + threadIdx.x;
  int stride = gridDim.x * blockDim.x;
  for (int j = i0; j < 1552 * 384; j += stride) {
    int gp = j / 384, k = j - gp * 384;
    int g;
    if (gp < 16) g = gp;
    else {
      int r = gp - 16;
      int q = r & 3, h = r >> 2;
      g = 16 + q * 384 + h;
    }
    wrP2[j] = f2bf(ldf(wr, (size_t)g * 385 + k, isbf));
  }
  for (int g = i0; g < 1552; g += stride) {
    biasC[g] = ldf(bk, g, isbf) + ldf(br, g, isbf);
    wlC[g] = ldf(wk, (size_t)g * 8193 + 8192, isbf) + ldf(wr, g * 385 + 384, isbf);
  }
}

__global__ void k_repack_wc(const void* __restrict__ wc, u16* __restrict__ wcp,
                            const int* __restrict__ flagp) {
  int isbf = *flagp;
  int i0 = blockIdx.x * blockDim.x + threadIdx.x;
  int stride = gridDim.x * blockDim.x;
  for (int j = i0; j < 384 * 3840; j += stride) {
    int o = j / 3840;
    int r = j - o * 3840;
    int k = r / 384;
    int h = r - k * 384;
    wcp[j] = f2bf(ldf(wc, (o * 384 + h) * 10 + k, isbf));  // [o][h][k]->[o][k][h]
  }
}

// canonical fp32: [vt 12800][Ws 24576][bs 64][Wrs 24576][brs 384][bc 384]
//                 [Wo 49152][bo 128]  (total 112064 floats)
__global__ void k_cvt_smalls(const void* vt, const void* Ws, const void* bs,
                             const void* Wrs, const void* brs, const void* bc,
                             const void* Wo, const void* bo,
                             float* __restrict__ dst, const int* __restrict__ flagp) {
  int isbf = *flagp;
  int i = blockIdx.x * blockDim.x + threadIdx.x;
  int stride = gridDim.x * blockDim.x;
  for (; i < 112064; i += stride) {
    float v;
    if (i < 12800) v = ldf(vt, i, isbf);
    else if (i < 37376) v = ldf(Ws, i - 12800, isbf);
    else if (i < 37440) v = ldf(bs, i - 37376, isbf);
    else if (i < 62016) v = ldf(Wrs, i - 37440, isbf);
    else if (i < 62400) v = ldf(brs, i - 62016, isbf);
    else if (i < 62784) v = ldf(bc, i - 62400, isbf);
    else if (i < 111936) v = ldf(Wo, i - 62784, isbf);
    else v = ldf(bo, i - 111936, isbf);
    dst[i] = v;
  }
}

__global__ void k_zero(float* __restrict__ p, int n) {
  int i = blockIdx.x * blockDim.x + threadIdx.x;
  int stride = gridDim.x * blockDim.x;
  for (; i < n; i += stride) p[i] = 0.f;
}

// ------------------------- PH1: gathered GEMM, swizzled GLL staging --------
// grid (100 m-tiles, 13 g-tiles) — m FAST so each Wk g-panel stays L2/LLC-hot.
// Tile 128x128, BK=64 bf16. Epilogue writes XKb permuted-transposed [t][b][g'].
__global__ __launch_bounds__(256) void k_gemm_xk(
    const int* __restrict__ node_ids, const u16* __restrict__ embB,
    const u16* __restrict__ wkp, const float* __restrict__ vtF,
    const float* __restrict__ biasC, const float* __restrict__ wlC,
    u16* __restrict__ xkb) {
  __shared__ alignas(16) u16 As[128 * 64];
  __shared__ alignas(16) u16 Bs[128 * 64];
  int tid = threadIdx.x;
  int m0 = blockIdx.x * 128;
  int g0 = blockIdx.y * 128;
  int lane = tid & 63, w = tid >> 6;
  int wy = w >> 1, wx = w & 1;
  f32x4 acc[4][4];
#pragma unroll
  for (int i = 0; i < 4; ++i)
#pragma unroll
    for (int j = 0; j < 4; ++j) acc[i][j] = (f32x4){0.f, 0.f, 0.f, 0.f};

  int l15 = lane & 15, lq = lane >> 4;
  int lr = lane >> 3, lc = lane & 7;  // row-in-chunk, 16B-chunk slot
  int swc = (lc ^ lr) * 8;            // swizzled global chunk offset (u16)
  int cRd = (lq ^ (l15 & 7)) * 8;     // swizzled read chunk, ks=0 (u16)

  for (int kt = 0; kt < 128; ++kt) {
    __syncthreads();
    // ---- stage A (gathered embed rows), swizzled global chunk
#pragma unroll
    for (int c = 0; c < 4; ++c) {
      int chunk = w * 4 + c;
      int r = chunk * 8 + lr;
      int id = node_ids[(size_t)(m0 + r) * 64 + (kt >> 1)];
      const u16* gp = embB + (size_t)id * 128 + (kt & 1) * 64 + swc;
      u16* lp = As + chunk * 512 + lane * 8;
      GLL(gp, lp);
    }
    // ---- stage B (Wk tile), swizzled global chunk
#pragma unroll
    for (int c = 0; c < 4; ++c) {
      int chunk = w * 4 + c;
      int r = chunk * 8 + lr;
      const u16* gp = wkp + (size_t)(g0 + r) * 8192 + (size_t)kt * 64 + swc;
      u16* lp = Bs + chunk * 512 + lane * 8;
      GLL(gp, lp);
    }
    __syncthreads();
    const u16* Ab = As + (wy * 64 + l15) * 64;
    const u16* Bb = Bs + (wx * 64 + l15) * 64;
#pragma unroll
    for (int ks = 0; ks < 2; ++ks) {
      int co = cRd ^ (ks * 32);
      bf16x8 av[4], bv[4];
#pragma unroll
      for (int i = 0; i < 4; ++i) av[i] = *(const bf16x8*)(Ab + i * 1024 + co);
#pragma unroll
      for (int j = 0; j < 4; ++j) bv[j] = *(const bf16x8*)(Bb + j * 1024 + co);
#pragma unroll
      for (int i = 0; i < 4; ++i)
#pragma unroll
        for (int j = 0; j < 4; ++j)
          acc[i][j] =
              __builtin_amdgcn_mfma_f32_16x16x32_bf16(av[i], bv[j], acc[i][j], 0, 0, 0);
    }
  }
  float vt[4][4];
#pragma unroll
  for (int i = 0; i < 4; ++i)
#pragma unroll
    for (int p = 0; p < 4; ++p)
      vt[i][p] = vtF[m0 + wy * 64 + i * 16 + lq * 4 + p];
#pragma unroll
  for (int j = 0; j < 4; ++j) {
    int gcol = g0 + wx * 64 + j * 16 + l15;
    if (gcol < 1552) {
      float bC = biasC[gcol], wC = wlC[gcol];
      int gp;
      if (gcol < 16) gp = gcol;
      else {
        int r = gcol - 16;
        int h = r % 384, q = r / 384;
        gp = 16 + h * 4 + q;
      }
#pragma unroll
      for (int i = 0; i < 4; ++i)
#pragma unroll
        for (int p = 0; p < 4; ++p) {
          int grow = m0 + wy * 64 + i * 16 + lq * 4 + p;
          int b = grow / 50, t = grow - b * 50;
          xkb[((size_t)t * 256 + b) * 1552 + gp] =
              f2bf(acc[i][j][p] + bC + vt[i][p] * wC);
        }
    }
  }
}

// ------------------------- PH2: g-split persistent scan --------------------
// 192 blocks = 16 b-groups x 12 g-slices (XCD-aligned swizzle: a group's 12
// blocks share one XCD's L2). Per block: 113KB Wr slab LDS-resident (rows
// 0..15 = fm/im, 16..143 = its 128 permuted gate rows), loaded ONCE.
// Per step: stage h_{t-1} (12.3KB, double-buffered global) -> LDS; MFMA
// A=Wr,B=h => lane holds 4 gate pre-acts of one (h,b); fm/im tile computed
// redundantly (wave 0); gates in-register (creg scalar/lane); write h ->
// hx[(t+1)&1] + hbuf; 12-block group barrier (monotonic atomic counter).
__global__ __launch_bounds__(512, 2) void k_scan2(
    const u16* __restrict__ xkb,   // [50][256][1552] bf16 permuted g'
    const u16* __restrict__ wrP2,  // [1552][384] bf16 permuted g'
    float* __restrict__ hbuf,      // [50][256][384] f32
    float* __restrict__ dbuf,      // [50][256]
    u16* __restrict__ hx,          // [2][256][384] bf16 (hx[0] zeroed)
    int* __restrict__ barCnt) {    // [16] zeroed
  __shared__ alignas(16) u16 WrS[144 * 392];
  __shared__ alignas(16) u16 hS[16 * 392];
  __shared__ alignas(16) float fmTile[16 * 17];
  __shared__ float fmS[16][8], imS[16][8];

  int tid = threadIdx.x;
  // XCD-aligned swizzle: xcd = L%8 hosts b-groups {2*xcd, 2*xcd+1}
  int L = blockIdx.x;
  int xcd = L & 7, kk = L >> 3;           // kk in [0,24)
  int hi = (kk >= 12) ? 1 : 0;
  int bg = (xcd << 1) | hi;               // b-group [0,16)
  int gs = kk - 12 * hi;                  // g-slice [0,12)
  int b0 = bg * 16;
  int wv = tid >> 6, lane = tid & 63, l15 = lane & 15, lq = lane >> 4;

  // ---- one-time: Wr slab -> LDS (144 rows x 384, padded stride 392)
  for (int idx = tid; idx < 144 * 48; idx += 512) {
    int r = idx / 48, c = idx - r * 48;
    int gr = (r < 16) ? r : (16 + gs * 128 + (r - 16));
    uint4 v = *(const uint4*)(wrP2 + (size_t)gr * 384 + c * 8);
    *(uint4*)(WrS + r * 392 + c * 8) = v;
  }

  int hmy = gs * 32 + wv * 4 + lq;   // this lane's h in [0,384)
  int lmy = hmy / 48;                // level index
  int bmy = b0 + l15;                // this lane's batch row
  float creg = 0.f;

  const u16* arow_g = WrS + (16 + wv * 16 + l15) * 392 + lq * 8;
  const u16* arow_f = WrS + l15 * 392 + lq * 8;
  const u16* brow = hS + l15 * 392 + lq * 8;

  __syncthreads();

  for (int t = 0; t < 50; ++t) {
    // ---- phase 1: XK reg-prefetch + stage h_{t-1} -> hS
    uint2 xkg = *(const uint2*)(xkb + ((size_t)t * 256 + bmy) * 1552 + 16 +
                                gs * 128 + wv * 16 + lq * 4);
    uint4 xksm;
    if (tid < 32) {
      int r = tid & 15;
      xksm = *(const uint4*)(xkb + ((size_t)t * 256 + b0 + r) * 1552 +
                             ((tid < 16) ? 0 : 8));
    }
    {
      const u16* hsrc = hx + (size_t)(t & 1) * (256 * 384) + (size_t)b0 * 384;
      for (int idx = tid; idx < 768; idx += 512) {
        int r = idx / 48, c = idx - r * 48;
        uint4 v = *(const uint4*)(hsrc + r * 384 + c * 8);
        *(uint4*)(hS + r * 392 + c * 8) = v;
      }
    }
    __syncthreads();

    // ---- phase 2: GEMM (A=Wr rows g', B=h rows b)
    f32x4 accg = (f32x4){0.f, 0.f, 0.f, 0.f};
    f32x4 accf = (f32x4){0.f, 0.f, 0.f, 0.f};
#pragma unroll
    for (int ks = 0; ks < 12; ++ks) {
      bf16x8 bv = *(const bf16x8*)(brow + ks * 32);
      bf16x8 ag = *(const bf16x8*)(arow_g + ks * 32);
      accg = __builtin_amdgcn_mfma_f32_16x16x32_bf16(ag, bv, accg, 0, 0, 0);
      if (wv == 0) {
        bf16x8 afm = *(const bf16x8*)(arow_f + ks * 32);
        accf = __builtin_amdgcn_mfma_f32_16x16x32_bf16(afm, bv, accf, 0, 0, 0);
      }
    }
    if (wv == 0) {
#pragma unroll
      for (int p = 0; p < 4; ++p) fmTile[(lq * 4 + p) * 17 + l15] = accf[p];
    }
    __syncthreads();

    // ---- phase 3: fm/im softmax (fm: tid<16, im: tid 16..31)
    if (tid < 32) {
      int r = tid & 15;
      const u16* xs = (const u16*)&xksm;
      float z[8], m = -1e30f;
#pragma unroll
      for (int j = 0; j < 8; ++j) {
        int jj = (tid < 16) ? j : (8 + j);
        z[j] = fmTile[jj * 17 + r] + bf2f(xs[j]);
        m = fmaxf(m, z[j]);
      }
      float s = 0.f;
#pragma unroll
      for (int j = 0; j < 8; ++j) { z[j] = __expf(z[j] - m); s += z[j]; }
      float inv = 1.f / s;
      if (tid < 16) {
        float run = 0.f, fsum = 0.f;
#pragma unroll
        for (int j = 0; j < 8; ++j) { run += z[j] * inv; fmS[r][j] = run; fsum += run; }
        if (gs == 0) dbuf[(size_t)t * 256 + b0 + r] = 1.f - fsum * 0.125f;
      } else {
        float run = 0.f;
#pragma unroll
        for (int j = 7; j >= 0; --j) { run += z[j] * inv; imS[r][j] = run; }
      }
    }
    __syncthreads();

    // ---- phase 4: gates, fully in-register (one (h,b) per lane)
    {
      const u16* xg = (const u16*)&xkg;
      float x0 = accg[0] + bf2f(xg[0]);
      float x1 = accg[1] + bf2f(xg[1]);
      float x2 = accg[2] + bf2f(xg[2]);
      float x3 = accg[3] + bf2f(xg[3]);
      float fg = sigf(x0), ig = sigf(x1), og = sigf(x2), ci = tanhf_(x3);
      float fm = fmS[l15][lmy], im = imS[l15][lmy];
      float ov = fm * im;
      float cn = ov * (fg * creg + ig * ci) + (fm - ov) * creg + (im - ov) * ci;
      float hn = og * tanhf_(cn);
      creg = cn;
      hbuf[((size_t)t * 256 + bmy) * 384 + hmy] = hn;
      hx[(size_t)((t + 1) & 1) * (256 * 384) + (size_t)bmy * 384 + hmy] = f2bf(hn);
    }

    // ---- phase 5: 12-block group barrier (skip after last step)
    if (t != 49) {
      __threadfence();
      __syncthreads();
      if (tid == 0) {
        __hip_atomic_fetch_add(&barCnt[bg], 1, __ATOMIC_RELEASE,
                               __HIP_MEMORY_SCOPE_AGENT);
        while (__hip_atomic_load(&barCnt[bg], __ATOMIC_ACQUIRE,
                                 __HIP_MEMORY_SCOPE_AGENT) < 12 * (t + 1)) {
          __builtin_amdgcn_s_sleep(2);
        }
      }
      __syncthreads();
      __threadfence();
    }
  }
}

// ------------------------- PH3: final (theme/conv/out) ---------------------
__global__ __launch_bounds__(384) void k_final(
    const float* __restrict__ hbuf, const float* __restrict__ dbuf,
    const unsigned char* __restrict__ am, const float* __restrict__ smalls,
    const u16* __restrict__ wcp, float* __restrict__ out) {
  const float* WsF = smalls + 12800;
  const float* bsF = smalls + 37376;
  const float* WrsF = smalls + 37440;
  const float* brsF = smalls + 62016;
  const float* bcF = smalls + 62400;
  const float* WoF = smalls + 62784;
  const float* boF = smalls + 111936;
  __shared__ alignas(16) float lh2[10][384];
  __shared__ alignas(16) float ti[384];
  __shared__ alignas(16) float us[64];
  __shared__ alignas(16) float rnnS[384];
  __shared__ alignas(16) float hlastS[384];
  __shared__ float ldS[10];
  __shared__ int npad[50];
  __shared__ int lastS;
  int tid = threadIdx.x;
  int b = blockIdx.x;

  if (tid < 50) {
    const unsigned char* mr = am + ((size_t)b * 50 + tid) * 64;
    int all1 = 1;
    for (int q = 0; q < 64; ++q) all1 &= (mr[q] != 0);
    npad[tid] = all1 ? 0 : 1;
  }
  __syncthreads();
  if (tid == 0) {
    int c = 0;
    for (int v = 0; v < 50; ++v) c += npad[v];
    int lv = c - 1;
    int last = lv < 0 ? 0 : lv;
    lastS = last;
    float cum = 0.f, cv[10];
    for (int k = 0; k < 10; ++k) {
      int s = last - 9 + k;
      float dk = (s >= 0) ? dbuf[(size_t)s * 256 + b] : 0.f;
      cum += dk;
      cv[k] = cum;
    }
    float m = cv[0];
    for (int k = 1; k < 10; ++k) m = fmaxf(m, cv[k]);
    float ssum = 0.f, ee[10];
    for (int k = 0; k < 10; ++k) { ee[k] = __expf(cv[k] - m); ssum += ee[k]; }
    float inv = 1.f / ssum;
    for (int k = 0; k < 10; ++k) ldS[k] = ee[k] * inv;
  }
  __syncthreads();
  {  // local_h, theme input, h_last
    int h = tid;
    int last = lastS;
    float ssum = 0.f;
    for (int k = 0; k < 10; ++k) {
      int s = last - 9 + k;
      float hv = (s >= 0) ? hbuf[((size_t)s * 256 + b) * 384 + h] : 0.f;
      float v = hv * ldS[k];
      lh2[k][h] = v;
      ssum += v;
    }
    ti[h] = ssum * 0.1f;
    hlastS[h] = hbuf[((size_t)last * 256 + b) * 384 + h];
  }
  __syncthreads();
  if (tid < 64) {  // u = relu(ti @ Ws^T + bs)
    float a = bsF[tid];
    const float* wr = WsF + (size_t)tid * 384;
    for (int h = 0; h < 384; ++h) a += wr[h] * ti[h];
    us[tid] = fmaxf(a, 0.f);
  }
  __syncthreads();
  {  // theme = sigmoid(u @ Wrs^T + brs); conv; rnn = theme*conv + h_last
    int o = tid;
    float th = brsF[o];
    const float* wr = WrsF + (size_t)o * 64;
    for (int k = 0; k < 64; ++k) th += wr[k] * us[k];
    th = sigf(th);
    float cacc = bcF[o];
    for (int k = 0; k < 10; ++k) {
      const u16* wrow = wcp + ((size_t)o * 10 + k) * 384;
      const float* lrow = lh2[k];
      for (int h8 = 0; h8 < 48; ++h8) cacc += dot8_bf(wrow + h8 * 8, lrow + h8 * 8);
    }
    rnnS[o] = th * cacc + hlastS[o];
  }
  __syncthreads();
  if (tid < 128) {  // out = rnn @ Wo^T + bo, fp32
    float a = boF[tid];
    const float* wr = WoF + (size_t)tid * 384;
    for (int h = 0; h < 384; ++h) a += wr[h] * rnnS[h];
    out[(size_t)b * 128 + tid] = a;
  }
}

// ------------------------- launch ------------------------------------------
extern "C" void kernel_launch(void* const* d_in, const int* in_sizes, int n_in,
                              void* d_out, int out_size, void* d_ws, size_t ws_size,
                              hipStream_t stream) {
  const int* node_ids = (const int*)d_in[0];
  const void* vtR = d_in[3];
  const unsigned char* am = (const unsigned char*)d_in[5];
  const void* embR = d_in[6];
  const void* WkR = d_in[7];
  const void* bkR = d_in[8];
  const void* WrR = d_in[9];
  const void* brR = d_in[10];
  const void* WsR = d_in[11];
  const void* bsR = d_in[12];
  const void* WrsR = d_in[13];
  const void* brsR = d_in[14];
  const void* WcR = d_in[15];
  const void* bcR = d_in[16];
  const void* WoR = d_in[17];
  const void* boR = d_in[18];
  (void)in_sizes; (void)n_in; (void)out_size; (void)ws_size;

  char* ws = (char*)d_ws;
  size_t off = 0;
  auto alloc = [&](size_t bytes) {
    void* p = ws + off;
    off = (off + bytes + 255) & ~(size_t)255;
    return p;
  };
  int* flagp = (int*)alloc(4);
  u16* embB = (u16*)alloc((size_t)10001 * 128 * 2);      // 2.56MB
  u16* WkP = (u16*)alloc((size_t)1664 * 8192 * 2);       // 27.3MB
  u16* WrP2 = (u16*)alloc((size_t)1552 * 384 * 2);       // 1.19MB bf16 permuted
  float* biasC = (float*)alloc(1552 * 4);
  float* wlC = (float*)alloc(1552 * 4);
  float* smalls = (float*)alloc((size_t)112064 * 4);
  u16* XKb = (u16*)alloc((size_t)12800 * 1552 * 2);      // 39.7MB [t][b][g']
  u16* WcP = (u16*)alloc((size_t)384 * 3840 * 2);        // 2.9MB
  float* Hbuf = (float*)alloc((size_t)50 * 256 * 384 * 4);  // 19.7MB
  float* Dbuf = (float*)alloc((size_t)50 * 256 * 4);
  u16* Hx = (u16*)alloc((size_t)2 * 256 * 384 * 2);      // 393KB
  int* BarCnt = (int*)alloc(16 * 4);

  k_detect<<<dim3(1), dim3(64), 0, stream>>>((const unsigned int*)embR, flagp);
  k_cvt_emb<<<dim3(1024), dim3(256), 0, stream>>>(embR, embB, flagp);
  k_repack_wk<<<dim3(2048), dim3(256), 0, stream>>>(WkR, WkP, flagp);
  k_prep_wr2<<<dim3(512), dim3(256), 0, stream>>>(WrR, WkR, bkR, brR, WrP2, biasC,
                                                  wlC, flagp);
  k_repack_wc<<<dim3(512), dim3(256), 0, stream>>>(WcR, WcP, flagp);
  k_cvt_smalls<<<dim3(128), dim3(256), 0, stream>>>(vtR, WsR, bsR, WrsR, brsR,
                                                    bcR, WoR, boR, smalls, flagp);
  k_zero<<<dim3(96), dim3(256), 0, stream>>>((float*)Hx, 2 * 256 * 384 / 2);
  k_zero<<<dim3(1), dim3(64), 0, stream>>>((float*)BarCnt, 16);

  k_gemm_xk<<<dim3(100, 13), dim3(256), 0, stream>>>(node_ids, embB, WkP, smalls,
                                                     biasC, wlC, XKb);

  k_scan2<<<dim3(192), dim3(512), 0, stream>>>(XKb, WrP2, Hbuf, Dbuf, Hx, BarCnt);

  k_final<<<dim3(256), dim3(384), 0, stream>>>(Hbuf, Dbuf, am, smalls, WcP,
                                               (float*)d_out);
}

// Round 4
// 2853.549 us; speedup vs baseline: 1.5032x; 1.5032x over previous
//
#include <hip/hip_runtime.h>
#include <stdint.h>

// ---------------------------------------------------------------------------
// StageNet forward on MI355X — ROUND 15.
// R14 (3490us) post-mortem: per-step __threadfence + acquire/release atomics
// = L2 wb/inv per block-step on non-coherent-XCD hardware -> memory system
// thrash (VALUBusy 0.59%). RULE: no per-step cross-block sync on this chip.
// This round: self-contained blocks with Wr REGISTER-RESIDENT:
//  * k_scan3: 16 blocks x 1024 thr (16 waves). Wr (permuted g', 97 tiles of
//    16 rows) lives in VGPRs: 6 tiles/wave x 12 ks x bf16x8 = 288 VGPR/lane
//    (tiles T = i*16+w), tile 96 in LDS (wave 15). Per step: 12 ds_read_b128
//    h B-frags + 72 reg-operand MFMAs/wave + in-register gates (lane's
//    D-frag = the 4 gate pre-acts of one (b,h); creg scalar/lane/tile) +
//    fm/im = tile0 MFMA (wave 0) -> LDS -> 32-lane softmax. 3 syncthreads,
//    ZERO atomics/fences. Global per step: 48KB XK read + 24KB hbuf write.
//  * k_gemm_xk keeps R14 m-fast grid (Wk panel L2-hot) + [t][b][g'] epilogue.
// Predicted: k_scan3 150-250us, gemm ~450-550, total ~0.8-0.95ms.
// ---------------------------------------------------------------------------

typedef unsigned short u16;
typedef short bf16x8 __attribute__((ext_vector_type(8)));
typedef float f32x4 __attribute__((ext_vector_type(4)));

#define GLL(gp, lp)                                                            \
  __builtin_amdgcn_global_load_lds(                                            \
      (const __attribute__((address_space(1))) unsigned int*)(gp),             \
      (__attribute__((address_space(3))) unsigned int*)(lp), 16, 0, 0)

__device__ __forceinline__ float bf2f(u16 u) {
  union { unsigned int i; float f; } v;
  v.i = ((unsigned int)u) << 16;
  return v.f;
}
__device__ __forceinline__ u16 f2bf(float f) {
  union { float f; unsigned int i; } v;
  v.f = f;
  unsigned int r = (v.i + 0x7fffu + ((v.i >> 16) & 1u)) >> 16;
  return (u16)r;
}
__device__ __forceinline__ float ldf(const void* p, size_t i, int isbf) {
  return isbf ? bf2f(((const u16*)p)[i]) : ((const float*)p)[i];
}
__device__ __forceinline__ float sigf(float x) { return 1.f / (1.f + __expf(-x)); }
__device__ __forceinline__ float tanhf_(float x) {
  float cx = fminf(fmaxf(x, -15.f), 15.f);
  float e = __expf(2.f * cx);
  return (e - 1.f) / (e + 1.f);
}
__device__ __forceinline__ float dot8_bf(const u16* w, const float* lp) {
  uint4 wv = *(const uint4*)w;
  union { unsigned int u; float f; } a0, a1;
  float s;
  a0.u = wv.x << 16; a1.u = wv.x & 0xffff0000u;
  s = lp[0] * a0.f + lp[1] * a1.f;
  a0.u = wv.y << 16; a1.u = wv.y & 0xffff0000u;
  s += lp[2] * a0.f + lp[3] * a1.f;
  a0.u = wv.z << 16; a1.u = wv.z & 0xffff0000u;
  s += lp[4] * a0.f + lp[5] * a1.f;
  a0.u = wv.w << 16; a1.u = wv.w & 0xffff0000u;
  s += lp[6] * a0.f + lp[7] * a1.f;
  return s;
}

// ------------------------- dtype detection (safety) ------------------------
__global__ void k_detect(const unsigned int* __restrict__ emb_raw,
                         int* __restrict__ flag) {
  if (blockIdx.x == 0 && threadIdx.x == 0) {
    int cnt = 0;
    for (int i = 64; i < 128; ++i) {
      unsigned int u = emb_raw[i];
      unsigned int lo = u & 0xffffu;
      unsigned int ex = (lo >> 7) & 0xffu;
      if (lo != 0 && ex >= 100 && ex <= 126) ++cnt;
    }
    *flag = (cnt >= 32) ? 1 : 0;
  }
}

// ------------------------- canonicalization --------------------------------
__global__ void k_cvt_emb(const void* __restrict__ src, u16* __restrict__ dst,
                          const int* __restrict__ flagp) {
  int isbf = *flagp;
  int n = 10001 * 128;
  int i = blockIdx.x * blockDim.x + threadIdx.x;
  int stride = gridDim.x * blockDim.x;
  for (; i < n; i += stride)
    dst[i] = isbf ? ((const u16*)src)[i] : f2bf(((const float*)src)[i]);
}

__global__ void k_repack_wk(const void* __restrict__ wk, u16* __restrict__ wkp,
                            const int* __restrict__ flagp) {
  int isbf = *flagp;
  size_t i = (size_t)blockIdx.x * blockDim.x + threadIdx.x;
  size_t total = (size_t)1664 * 8192;
  size_t stride = (size_t)gridDim.x * blockDim.x;
  for (; i < total; i += stride) {
    size_t g = i >> 13, k = i & 8191;
    wkp[i] = (g < 1552) ? f2bf(ldf(wk, g * 8193 + k, isbf)) : (u16)0;
  }
}

// wrP2[g'][k] bf16 (permuted g'): g'<16 -> g'=g ; else g'=16+4h+q <-> g=16+q*384+h
__global__ void k_prep_wr2(const void* __restrict__ wr, const void* __restrict__ wk,
                           const void* __restrict__ bk, const void* __restrict__ br,
                           u16* __restrict__ wrP2, float* __restrict__ biasC,
                           float* __restrict__ wlC, const int* __restrict__ flagp) {
  int isbf = *flagp;
  int i0 = blockIdx.x * blockDim.x + threadIdx.x;
  int stride = gridDim.x * blockDim.x;
  for (int j = i0; j < 1552 * 384; j += stride) {
    int gp = j / 384, k = j - gp * 384;
    int g;
    if (gp < 16) g = gp;
    else {
      int r = gp - 16;
      int q = r & 3, h = r >> 2;
      g = 16 + q * 384 + h;
    }
    wrP2[j] = f2bf(ldf(wr, (size_t)g * 385 + k, isbf));
  }
  for (int g = i0; g < 1552; g += stride) {
    biasC[g] = ldf(bk, g, isbf) + ldf(br, g, isbf);
    wlC[g] = ldf(wk, (size_t)g * 8193 + 8192, isbf) + ldf(wr, g * 385 + 384, isbf);
  }
}

__global__ void k_repack_wc(const void* __restrict__ wc, u16* __restrict__ wcp,
                            const int* __restrict__ flagp) {
  int isbf = *flagp;
  int i0 = blockIdx.x * blockDim.x + threadIdx.x;
  int stride = gridDim.x * blockDim.x;
  for (int j = i0; j < 384 * 3840; j += stride) {
    int o = j / 3840;
    int r = j - o * 3840;
    int k = r / 384;
    int h = r - k * 384;
    wcp[j] = f2bf(ldf(wc, (o * 384 + h) * 10 + k, isbf));  // [o][h][k]->[o][k][h]
  }
}

// canonical fp32: [vt 12800][Ws 24576][bs 64][Wrs 24576][brs 384][bc 384]
//                 [Wo 49152][bo 128]  (total 112064 floats)
__global__ void k_cvt_smalls(const void* vt, const void* Ws, const void* bs,
                             const void* Wrs, const void* brs, const void* bc,
                             const void* Wo, const void* bo,
                             float* __restrict__ dst, const int* __restrict__ flagp) {
  int isbf = *flagp;
  int i = blockIdx.x * blockDim.x + threadIdx.x;
  int stride = gridDim.x * blockDim.x;
  for (; i < 112064; i += stride) {
    float v;
    if (i < 12800) v = ldf(vt, i, isbf);
    else if (i < 37376) v = ldf(Ws, i - 12800, isbf);
    else if (i < 37440) v = ldf(bs, i - 37376, isbf);
    else if (i < 62016) v = ldf(Wrs, i - 37440, isbf);
    else if (i < 62400) v = ldf(brs, i - 62016, isbf);
    else if (i < 62784) v = ldf(bc, i - 62400, isbf);
    else if (i < 111936) v = ldf(Wo, i - 62784, isbf);
    else v = ldf(bo, i - 111936, isbf);
    dst[i] = v;
  }
}

// ------------------------- PH1: gathered GEMM, swizzled GLL staging --------
// grid (100 m-tiles, 13 g-tiles) — m FAST so each Wk g-panel stays L2/LLC-hot.
// Tile 128x128, BK=64 bf16. Epilogue writes XKb permuted-transposed [t][b][g'].
__global__ __launch_bounds__(256) void k_gemm_xk(
    const int* __restrict__ node_ids, const u16* __restrict__ embB,
    const u16* __restrict__ wkp, const float* __restrict__ vtF,
    const float* __restrict__ biasC, const float* __restrict__ wlC,
    u16* __restrict__ xkb) {
  __shared__ alignas(16) u16 As[128 * 64];
  __shared__ alignas(16) u16 Bs[128 * 64];
  int tid = threadIdx.x;
  int m0 = blockIdx.x * 128;
  int g0 = blockIdx.y * 128;
  int lane = tid & 63, w = tid >> 6;
  int wy = w >> 1, wx = w & 1;
  f32x4 acc[4][4];
#pragma unroll
  for (int i = 0; i < 4; ++i)
#pragma unroll
    for (int j = 0; j < 4; ++j) acc[i][j] = (f32x4){0.f, 0.f, 0.f, 0.f};

  int l15 = lane & 15, lq = lane >> 4;
  int lr = lane >> 3, lc = lane & 7;  // row-in-chunk, 16B-chunk slot
  int swc = (lc ^ lr) * 8;            // swizzled global chunk offset (u16)
  int cRd = (lq ^ (l15 & 7)) * 8;     // swizzled read chunk, ks=0 (u16)

  for (int kt = 0; kt < 128; ++kt) {
    __syncthreads();
    // ---- stage A (gathered embed rows), swizzled global chunk
#pragma unroll
    for (int c = 0; c < 4; ++c) {
      int chunk = w * 4 + c;
      int r = chunk * 8 + lr;
      int id = node_ids[(size_t)(m0 + r) * 64 + (kt >> 1)];
      const u16* gp = embB + (size_t)id * 128 + (kt & 1) * 64 + swc;
      u16* lp = As + chunk * 512 + lane * 8;
      GLL(gp, lp);
    }
    // ---- stage B (Wk tile), swizzled global chunk
#pragma unroll
    for (int c = 0; c < 4; ++c) {
      int chunk = w * 4 + c;
      int r = chunk * 8 + lr;
      const u16* gp = wkp + (size_t)(g0 + r) * 8192 + (size_t)kt * 64 + swc;
      u16* lp = Bs + chunk * 512 + lane * 8;
      GLL(gp, lp);
    }
    __syncthreads();
    const u16* Ab = As + (wy * 64 + l15) * 64;
    const u16* Bb = Bs + (wx * 64 + l15) * 64;
#pragma unroll
    for (int ks = 0; ks < 2; ++ks) {
      int co = cRd ^ (ks * 32);
      bf16x8 av[4], bv[4];
#pragma unroll
      for (int i = 0; i < 4; ++i) av[i] = *(const bf16x8*)(Ab + i * 1024 + co);
#pragma unroll
      for (int j = 0; j < 4; ++j) bv[j] = *(const bf16x8*)(Bb + j * 1024 + co);
#pragma unroll
      for (int i = 0; i < 4; ++i)
#pragma unroll
        for (int j = 0; j < 4; ++j)
          acc[i][j] =
              __builtin_amdgcn_mfma_f32_16x16x32_bf16(av[i], bv[j], acc[i][j], 0, 0, 0);
    }
  }
  float vt[4][4];
#pragma unroll
  for (int i = 0; i < 4; ++i)
#pragma unroll
    for (int p = 0; p < 4; ++p)
      vt[i][p] = vtF[m0 + wy * 64 + i * 16 + lq * 4 + p];
#pragma unroll
  for (int j = 0; j < 4; ++j) {
    int gcol = g0 + wx * 64 + j * 16 + l15;
    if (gcol < 1552) {
      float bC = biasC[gcol], wC = wlC[gcol];
      int gp;
      if (gcol < 16) gp = gcol;
      else {
        int r = gcol - 16;
        int h = r % 384, q = r / 384;
        gp = 16 + h * 4 + q;
      }
#pragma unroll
      for (int i = 0; i < 4; ++i)
#pragma unroll
        for (int p = 0; p < 4; ++p) {
          int grow = m0 + wy * 64 + i * 16 + lq * 4 + p;
          int b = grow / 50, t = grow - b * 50;
          xkb[((size_t)t * 256 + b) * 1552 + gp] =
              f2bf(acc[i][j][p] + bC + vt[i][p] * wC);
        }
    }
  }
}

// ------------------------- PH2: register-resident scan ---------------------
// 16 self-contained blocks (one per 16 batch rows), 1024 threads = 16 waves.
// g' space = 97 tiles of 16 rows (tile 0 = fm/im). Wave w holds tiles
// T = i*16+w (i<6) in VGPRs (288/lane); tile 96 in LDS (wave 15 computes).
// Per step: 12 ds_read_b128 h-frags; 6(+1) MFMA chains; lane's D-frag = the
// 4 gate pre-acts of (b=l15, h=4T+lq-4); gates in-register, creg/lane/tile;
// h -> hS (LDS, next step's B) + hbuf (global, k_final). NO cross-block ops.
__global__ __launch_bounds__(1024) void k_scan3(
    const u16* __restrict__ xkb,   // [50][256][1552] bf16, permuted g'
    const u16* __restrict__ wrP2,  // [1552][384] bf16, permuted g'
    float* __restrict__ hbuf,      // [50][256][384] f32
    float* __restrict__ dbuf) {    // [50][256] f32
  __shared__ alignas(16) u16 WrT[16 * 392];   // tile 96
  __shared__ alignas(16) u16 hS[16 * 392];
  __shared__ alignas(16) float fmTile[16 * 17];
  __shared__ float fmS[16][8], imS[16][8];

  int tid = threadIdx.x;
  int b0 = blockIdx.x * 16;
  int w = tid >> 6, lane = tid & 63, l15 = lane & 15, lq = lane >> 4;

  // one-time: LDS tile 96 + zero hS
  for (int idx = tid; idx < 16 * 48; idx += 1024) {
    int r = idx / 48, c = idx - r * 48;
    *(uint4*)(WrT + r * 392 + c * 8) =
        *(const uint4*)(wrP2 + (size_t)(96 * 16 + r) * 384 + c * 8);
  }
  for (int i = tid; i < 16 * 392; i += 1024) hS[i] = 0;

  // one-time: 6 register tiles per wave (T = i*16 + w)
  bf16x8 wrg[6][12];
#pragma unroll
  for (int i = 0; i < 6; ++i) {
    const u16* base = wrP2 + (size_t)((i * 16 + w) * 16 + l15) * 384 + lq * 8;
#pragma unroll
    for (int ks = 0; ks < 12; ++ks)
      wrg[i][ks] = *(const bf16x8*)(base + ks * 32);
  }
  float creg[7];
#pragma unroll
  for (int i = 0; i < 7; ++i) creg[i] = 0.f;
  __syncthreads();

  for (int t = 0; t < 50; ++t) {
    // ---- XK register prefetch (used 2 phases later)
    const u16* xkrow = xkb + ((size_t)t * 256 + b0 + l15) * 1552;
    uint2 xkg[6];
#pragma unroll
    for (int i = 0; i < 6; ++i)
      xkg[i] = *(const uint2*)(xkrow + (i * 16 + w) * 16 + lq * 4);
    uint2 xkg6;
    if (w == 15) xkg6 = *(const uint2*)(xkrow + 96 * 16 + lq * 4);
    else xkg6 = (uint2){0u, 0u};
    uint4 xksm = (uint4){0u, 0u, 0u, 0u};
    if (tid < 32)
      xksm = *(const uint4*)(xkb + ((size_t)t * 256 + b0 + (tid & 15)) * 1552 +
                             ((tid < 16) ? 0 : 8));

    // ---- B-frags (h_{t-1}) from LDS
    bf16x8 hb[12];
#pragma unroll
    for (int ks = 0; ks < 12; ++ks)
      hb[ks] = *(const bf16x8*)(hS + l15 * 392 + ks * 32 + lq * 8);

    // ---- MFMA chains (register A operands)
    f32x4 acc[6];
#pragma unroll
    for (int i = 0; i < 6; ++i) {
      f32x4 a = (f32x4){0.f, 0.f, 0.f, 0.f};
#pragma unroll
      for (int ks = 0; ks < 12; ++ks)
        a = __builtin_amdgcn_mfma_f32_16x16x32_bf16(wrg[i][ks], hb[ks], a, 0, 0, 0);
      acc[i] = a;
    }
    f32x4 acc6 = (f32x4){0.f, 0.f, 0.f, 0.f};
    if (w == 15) {
#pragma unroll
      for (int ks = 0; ks < 12; ++ks) {
        bf16x8 at = *(const bf16x8*)(WrT + l15 * 392 + ks * 32 + lq * 8);
        acc6 = __builtin_amdgcn_mfma_f32_16x16x32_bf16(at, hb[ks], acc6, 0, 0, 0);
      }
    }
    if (w == 0) {
#pragma unroll
      for (int p = 0; p < 4; ++p) fmTile[(lq * 4 + p) * 17 + l15] = acc[0][p];
    }
    __syncthreads();

    // ---- fm/im softmax (fm: tid<16, im: tid 16..31)
    if (tid < 32) {
      int r = tid & 15;
      const u16* xs = (const u16*)&xksm;
      float z[8], m = -1e30f;
#pragma unroll
      for (int j = 0; j < 8; ++j) {
        int jj = (tid < 16) ? j : (8 + j);
        z[j] = fmTile[jj * 17 + r] + bf2f(xs[j]);
        m = fmaxf(m, z[j]);
      }
      float s = 0.f;
#pragma unroll
      for (int j = 0; j < 8; ++j) { z[j] = __expf(z[j] - m); s += z[j]; }
      float inv = 1.f / s;
      if (tid < 16) {
        float run = 0.f, fsum = 0.f;
#pragma unroll
        for (int j = 0; j < 8; ++j) { run += z[j] * inv; fmS[r][j] = run; fsum += run; }
        dbuf[(size_t)t * 256 + (b0 + r)] = 1.f - fsum * 0.125f;
      } else {
        float run = 0.f;
#pragma unroll
        for (int j = 7; j >= 0; --j) { run += z[j] * inv; imS[r][j] = run; }
      }
    }
    __syncthreads();

    // ---- gates, fully in-register (one (b,h) cell per lane per tile)
    float* hrow = hbuf + ((size_t)t * 256 + b0 + l15) * 384;
#pragma unroll
    for (int i = 0; i < 6; ++i) {
      if (i == 0 && w == 0) continue;  // tile 0 = fm/im, no gates
      int T = i * 16 + w;
      int h = 4 * T + lq - 4;
      const u16* xg = (const u16*)&xkg[i];
      float x0 = acc[i][0] + bf2f(xg[0]);
      float x1 = acc[i][1] + bf2f(xg[1]);
      float x2 = acc[i][2] + bf2f(xg[2]);
      float x3 = acc[i][3] + bf2f(xg[3]);
      float fg = sigf(x0), ig = sigf(x1), og = sigf(x2), ci = tanhf_(x3);
      int l = h / 48;
      float fm = fmS[l15][l], im = imS[l15][l];
      float ov = fm * im;
      float cn = ov * (fg * creg[i] + ig * ci) + (fm - ov) * creg[i] + (im - ov) * ci;
      float hn = og * tanhf_(cn);
      creg[i] = cn;
      hrow[h] = hn;
      hS[l15 * 392 + h] = f2bf(hn);
    }
    if (w == 15) {
      int h = 4 * 96 + lq - 4;  // 380..383
      const u16* xg = (const u16*)&xkg6;
      float x0 = acc6[0] + bf2f(xg[0]);
      float x1 = acc6[1] + bf2f(xg[1]);
      float x2 = acc6[2] + bf2f(xg[2]);
      float x3 = acc6[3] + bf2f(xg[3]);
      float fg = sigf(x0), ig = sigf(x1), og = sigf(x2), ci = tanhf_(x3);
      int l = h / 48;
      float fm = fmS[l15][l], im = imS[l15][l];
      float ov = fm * im;
      float cn = ov * (fg * creg[6] + ig * ci) + (fm - ov) * creg[6] + (im - ov) * ci;
      float hn = og * tanhf_(cn);
      creg[6] = cn;
      hrow[h] = hn;
      hS[l15 * 392 + h] = f2bf(hn);
    }
    __syncthreads();
  }
}

// ------------------------- PH3: final (theme/conv/out) ---------------------
__global__ __launch_bounds__(384) void k_final(
    const float* __restrict__ hbuf, const float* __restrict__ dbuf,
    const unsigned char* __restrict__ am, const float* __restrict__ smalls,
    const u16* __restrict__ wcp, float* __restrict__ out) {
  const float* WsF = smalls + 12800;
  const float* bsF = smalls + 37376;
  const float* WrsF = smalls + 37440;
  const float* brsF = smalls + 62016;
  const float* bcF = smalls + 62400;
  const float* WoF = smalls + 62784;
  const float* boF = smalls + 111936;
  __shared__ alignas(16) float lh2[10][384];
  __shared__ alignas(16) float ti[384];
  __shared__ alignas(16) float us[64];
  __shared__ alignas(16) float rnnS[384];
  __shared__ alignas(16) float hlastS[384];
  __shared__ float ldS[10];
  __shared__ int npad[50];
  __shared__ int lastS;
  int tid = threadIdx.x;
  int b = blockIdx.x;

  if (tid < 50) {
    const unsigned char* mr = am + ((size_t)b * 50 + tid) * 64;
    int all1 = 1;
    for (int q = 0; q < 64; ++q) all1 &= (mr[q] != 0);
    npad[tid] = all1 ? 0 : 1;
  }
  __syncthreads();
  if (tid == 0) {
    int c = 0;
    for (int v = 0; v < 50; ++v) c += npad[v];
    int lv = c - 1;
    int last = lv < 0 ? 0 : lv;
    lastS = last;
    float cum = 0.f, cv[10];
    for (int k = 0; k < 10; ++k) {
      int s = last - 9 + k;
      float dk = (s >= 0) ? dbuf[(size_t)s * 256 + b] : 0.f;
      cum += dk;
      cv[k] = cum;
    }
    float m = cv[0];
    for (int k = 1; k < 10; ++k) m = fmaxf(m, cv[k]);
    float ssum = 0.f, ee[10];
    for (int k = 0; k < 10; ++k) { ee[k] = __expf(cv[k] - m); ssum += ee[k]; }
    float inv = 1.f / ssum;
    for (int k = 0; k < 10; ++k) ldS[k] = ee[k] * inv;
  }
  __syncthreads();
  {  // local_h, theme input, h_last
    int h = tid;
    int last = lastS;
    float ssum = 0.f;
    for (int k = 0; k < 10; ++k) {
      int s = last - 9 + k;
      float hv = (s >= 0) ? hbuf[((size_t)s * 256 + b) * 384 + h] : 0.f;
      float v = hv * ldS[k];
      lh2[k][h] = v;
      ssum += v;
    }
    ti[h] = ssum * 0.1f;
    hlastS[h] = hbuf[((size_t)last * 256 + b) * 384 + h];
  }
  __syncthreads();
  if (tid < 64) {  // u = relu(ti @ Ws^T + bs)
    float a = bsF[tid];
    const float* wr = WsF + (size_t)tid * 384;
    for (int h = 0; h < 384; ++h) a += wr[h] * ti[h];
    us[tid] = fmaxf(a, 0.f);
  }
  __syncthreads();
  {  // theme = sigmoid(u @ Wrs^T + brs); conv; rnn = theme*conv + h_last
    int o = tid;
    float th = brsF[o];
    const float* wr = WrsF + (size_t)o * 64;
    for (int k = 0; k < 64; ++k) th += wr[k] * us[k];
    th = sigf(th);
    float cacc = bcF[o];
    for (int k = 0; k < 10; ++k) {
      const u16* wrow = wcp + ((size_t)o * 10 + k) * 384;
      const float* lrow = lh2[k];
      for (int h8 = 0; h8 < 48; ++h8) cacc += dot8_bf(wrow + h8 * 8, lrow + h8 * 8);
    }
    rnnS[o] = th * cacc + hlastS[o];
  }
  __syncthreads();
  if (tid < 128) {  // out = rnn @ Wo^T + bo, fp32
    float a = boF[tid];
    const float* wr = WoF + (size_t)tid * 384;
    for (int h = 0; h < 384; ++h) a += wr[h] * rnnS[h];
    out[(size_t)b * 128 + tid] = a;
  }
}

// ------------------------- launch ------------------------------------------
extern "C" void kernel_launch(void* const* d_in, const int* in_sizes, int n_in,
                              void* d_out, int out_size, void* d_ws, size_t ws_size,
                              hipStream_t stream) {
  const int* node_ids = (const int*)d_in[0];
  const void* vtR = d_in[3];
  const unsigned char* am = (const unsigned char*)d_in[5];
  const void* embR = d_in[6];
  const void* WkR = d_in[7];
  const void* bkR = d_in[8];
  const void* WrR = d_in[9];
  const void* brR = d_in[10];
  const void* WsR = d_in[11];
  const void* bsR = d_in[12];
  const void* WrsR = d_in[13];
  const void* brsR = d_in[14];
  const void* WcR = d_in[15];
  const void* bcR = d_in[16];
  const void* WoR = d_in[17];
  const void* boR = d_in[18];
  (void)in_sizes; (void)n_in; (void)out_size; (void)ws_size;

  char* ws = (char*)d_ws;
  size_t off = 0;
  auto alloc = [&](size_t bytes) {
    void* p = ws + off;
    off = (off + bytes + 255) & ~(size_t)255;
    return p;
  };
  int* flagp = (int*)alloc(4);
  u16* embB = (u16*)alloc((size_t)10001 * 128 * 2);      // 2.56MB
  u16* WkP = (u16*)alloc((size_t)1664 * 8192 * 2);       // 27.3MB
  u16* WrP2 = (u16*)alloc((size_t)1552 * 384 * 2);       // 1.19MB bf16 permuted
  float* biasC = (float*)alloc(1552 * 4);
  float* wlC = (float*)alloc(1552 * 4);
  float* smalls = (float*)alloc((size_t)112064 * 4);
  u16* XKb = (u16*)alloc((size_t)12800 * 1552 * 2);      // 39.7MB [t][b][g']
  u16* WcP = (u16*)alloc((size_t)384 * 3840 * 2);        // 2.9MB
  float* Hbuf = (float*)alloc((size_t)50 * 256 * 384 * 4);  // 19.7MB
  float* Dbuf = (float*)alloc((size_t)50 * 256 * 4);

  k_detect<<<dim3(1), dim3(64), 0, stream>>>((const unsigned int*)embR, flagp);
  k_cvt_emb<<<dim3(1024), dim3(256), 0, stream>>>(embR, embB, flagp);
  k_repack_wk<<<dim3(2048), dim3(256), 0, stream>>>(WkR, WkP, flagp);
  k_prep_wr2<<<dim3(512), dim3(256), 0, stream>>>(WrR, WkR, bkR, brR, WrP2, biasC,
                                                  wlC, flagp);
  k_repack_wc<<<dim3(512), dim3(256), 0, stream>>>(WcR, WcP, flagp);
  k_cvt_smalls<<<dim3(128), dim3(256), 0, stream>>>(vtR, WsR, bsR, WrsR, brsR,
                                                    bcR, WoR, boR, smalls, flagp);

  k_gemm_xk<<<dim3(100, 13), dim3(256), 0, stream>>>(node_ids, embB, WkP, smalls,
                                                     biasC, wlC, XKb);

  k_scan3<<<dim3(16), dim3(1024), 0, stream>>>(XKb, WrP2, Hbuf, Dbuf);

  k_final<<<dim3(256), dim3(384), 0, stream>>>(Hbuf, Dbuf, am, smalls, WcP,
                                               (float*)d_out);
}